// Round 3
// baseline (315.802 us; speedup 1.0000x reference)
//
#include <hip/hip_runtime.h>
#include <math.h>

// Problem constants (mask is all-true 160x160 -> nv=nh=10, fixed)
#define CPS 16
#define ENC 128
#define NH 10
#define NPATCH 100      // patches per batch image
#define BATCH 4
#define CCH 256         // input channels
#define WIDTH 160
#define HW 25600        // 160*160
#define ROWS_TOTAL 400  // BATCH*NPATCH

// ---------------------------------------------------------------------------
// K1: streaming channel-partial conv. Each block: one 5120-px chunk of one
// (branch,b) plane x 16 channels. Per channel, each wave reads a 5 KB
// contiguous run (5 independent 1 KB wave-loads); the 4 waves tile a 20 KB
// contiguous block-run. 16 channel-split blocks accumulate into a
// pixel-linear partial buffer via fp32 atomicAdd (zeroed beforehand).
// This replaces the old 1KB-read-then-jump-100KB pattern (stuck at 2.5 TB/s
// effective) with dense streaming runs.
// ---------------------------------------------------------------------------
__global__ __launch_bounds__(256) void conv_partial_kernel(
    const float* __restrict__ f1, const float* __restrict__ f2,
    const float* __restrict__ wci, const float* __restrict__ wcd,
    float* __restrict__ partial)
{
    int lane = threadIdx.x & 63;
    int wv   = threadIdx.x >> 6;

    int bid   = blockIdx.x;        // 0..639
    int cg    = bid & 15;          // channel group (16 ch each)
    int rest  = bid >> 4;          // 0..39
    int plane = rest & 7;          // branch*4 + b
    int pxc   = rest >> 3;         // 0..4
    int branch = plane >> 2;
    int b      = plane & 3;

    const float* f    = branch ? f2  : f1;
    const float* wsel = branch ? wcd : wci;   // uniform -> scalar loads
    int c0 = cg * 16;

    // wave wv owns contiguous px subrange [pxc*5120 + wv*1280, +1280)
    int pxbase = pxc * 5120 + wv * 1280 + lane * 4;
    const float* fb = f + ((size_t)(b * CCH + c0)) * HW + pxbase;

    float4 acc[5] = {};
    #pragma unroll 4
    for (int c = 0; c < 16; ++c) {
        float wc = wsel[c0 + c];               // wave-uniform scalar load
        const float* p = fb + (size_t)c * HW;
        #pragma unroll
        for (int j = 0; j < 5; ++j) {          // 5 independent 1KB wave-loads
            float4 v = *(const float4*)(p + j * 256);
            acc[j].x = fmaf(v.x, wc, acc[j].x);
            acc[j].y = fmaf(v.y, wc, acc[j].y);
            acc[j].z = fmaf(v.z, wc, acc[j].z);
            acc[j].w = fmaf(v.w, wc, acc[j].w);
        }
    }

    float* pp = partial + (size_t)plane * HW + pxbase;
    #pragma unroll
    for (int j = 0; j < 5; ++j) {
        atomicAdd(pp + j * 256 + 0, acc[j].x);
        atomicAdd(pp + j * 256 + 1, acc[j].y);
        atomicAdd(pp + j * 256 + 2, acc[j].z);
        atomicAdd(pp + j * 256 + 3, acc[j].w);
    }
}

// ---------------------------------------------------------------------------
// K2: gather conv partials (patch layout) + bias + ReLU, then per-row MLP
// (256 -> relu(w1) 256 -> w2 128) + LayerNorm. 4 rows/block, 256 threads.
// ---------------------------------------------------------------------------
__global__ __launch_bounds__(256) void mlp_ln_kernel(
    const float* __restrict__ partial,
    const float* __restrict__ bci,  const float* __restrict__ bcd,
    const float* __restrict__ w1i, const float* __restrict__ w2i,
    const float* __restrict__ gi,  const float* __restrict__ bli,
    const float* __restrict__ w1d, const float* __restrict__ w2d,
    const float* __restrict__ gd,  const float* __restrict__ bld,
    float* __restrict__ e)
{
    const int R = 4;
    __shared__ float xs[R][256];
    __shared__ float ys[R][256];
    __shared__ float zs[R][ENC];

    int tid    = threadIdx.x;
    int branch = blockIdx.x / 100;            // uniform
    int row0   = (blockIdx.x % 100) * R;

    const float* w1 = branch ? w1d : w1i;
    const float* w2 = branch ? w2d : w2i;
    const float* g  = branch ? gd  : gi;
    const float* bl = branch ? bld : bli;
    float bias      = branch ? bcd[0] : bci[0];

    // gather: row p, element j=tid -> pixel in plane (branch,b)
    {
        int hh = tid >> 4, ww = tid & 15;
        #pragma unroll
        for (int r = 0; r < R; ++r) {
            int prow  = row0 + r;                  // 0..399
            int b     = prow / 100;
            int patch = prow % 100;
            int pv = patch / 10, ph = patch % 10;
            int pixel = (pv * 16 + hh) * WIDTH + ph * 16 + ww;
            float v = partial[(size_t)(branch * BATCH + b) * HW + pixel] + bias;
            xs[r][tid] = fmaxf(v, 0.f);
        }
    }
    __syncthreads();

    // GEMM1: y[r][tid] = relu(dot(xs[r], w1[tid,:]))
    {
        float acc[R] = {0.f, 0.f, 0.f, 0.f};
        const float4* w1r = (const float4*)(w1 + (size_t)tid * 256);
        #pragma unroll 4
        for (int c4 = 0; c4 < 64; ++c4) {
            float4 wv = w1r[c4];
            #pragma unroll
            for (int r = 0; r < R; ++r) {
                float4 xv = *(const float4*)(&xs[r][c4 * 4]);   // LDS broadcast
                acc[r] = fmaf(xv.x, wv.x, acc[r]);
                acc[r] = fmaf(xv.y, wv.y, acc[r]);
                acc[r] = fmaf(xv.z, wv.z, acc[r]);
                acc[r] = fmaf(xv.w, wv.w, acc[r]);
            }
        }
        #pragma unroll
        for (int r = 0; r < R; ++r) ys[r][tid] = fmaxf(acc[r], 0.f);
    }
    __syncthreads();

    // GEMM2: z[r][m] = dot(ys[r], w2[m,:])  (512 outputs, 2 per thread)
    #pragma unroll
    for (int i = 0; i < 2; ++i) {
        int idx = tid + 256 * i;
        int r = idx >> 7, m = idx & 127;
        float acc = 0.f;
        const float4* w2r = (const float4*)(w2 + (size_t)m * 256);
        #pragma unroll 4
        for (int c4 = 0; c4 < 64; ++c4) {
            float4 wv = w2r[c4];
            float4 yv = *(const float4*)(&ys[r][c4 * 4]);       // LDS broadcast
            acc = fmaf(yv.x, wv.x, acc);
            acc = fmaf(yv.y, wv.y, acc);
            acc = fmaf(yv.z, wv.z, acc);
            acc = fmaf(yv.w, wv.w, acc);
        }
        zs[r][m] = acc;
    }
    __syncthreads();

    // LayerNorm: wave r handles row r (each lane owns 2 of 128 elements)
    int r = tid >> 6, lane = tid & 63;
    float a  = zs[r][lane];
    float b2 = zs[r][lane + 64];
    float s = a + b2;
    float q = a * a + b2 * b2;
    #pragma unroll
    for (int off = 32; off >= 1; off >>= 1) {
        s += __shfl_xor(s, off);
        q += __shfl_xor(q, off);
    }
    float mu  = s * (1.f / 128.f);
    float var = q * (1.f / 128.f) - mu * mu;
    float inv = 1.f / sqrtf(var + 1e-5f);
    float* erow = e + ((size_t)(branch * ROWS_TOTAL + row0 + r)) * ENC;
    erow[lane]      = (a  - mu) * inv * g[lane]      + bl[lane];
    erow[lane + 64] = (b2 - mu) * inv * g[lane + 64] + bl[lane + 64];
}

// ---------------------------------------------------------------------------
// K3: logits = scale * e1[b] @ e2[b]^T  (4 x 100 x 100) + transposed copy
// ---------------------------------------------------------------------------
__global__ __launch_bounds__(256) void logits_kernel(
    const float* __restrict__ e, const float* __restrict__ lsc,
    float* __restrict__ out)
{
    int gidx = blockIdx.x * 256 + threadIdx.x;
    if (gidx >= BATCH * NPATCH * NPATCH) return;
    float scale = expf(lsc[0]);

    int b    = gidx / (NPATCH * NPATCH);
    int rrem = gidx % (NPATCH * NPATCH);
    int n = rrem / NPATCH, m = rrem % NPATCH;

    const float4* e1 = (const float4*)(e + (size_t)(b * NPATCH + n) * ENC);
    const float4* e2 = (const float4*)(e + (size_t)(ROWS_TOTAL + b * NPATCH + m) * ENC);
    float acc = 0.f;
    #pragma unroll 8
    for (int c4 = 0; c4 < ENC / 4; ++c4) {
        float4 av = e1[c4], bv = e2[c4];
        acc = fmaf(av.x, bv.x, acc);
        acc = fmaf(av.y, bv.y, acc);
        acc = fmaf(av.z, bv.z, acc);
        acc = fmaf(av.w, bv.w, acc);
    }
    float L = scale * acc;
    out[gidx] = L;                                              // logits_per_img
    out[BATCH * NPATCH * NPATCH + b * NPATCH * NPATCH + m * NPATCH + n] = L; // transposed
}

extern "C" void kernel_launch(void* const* d_in, const int* in_sizes, int n_in,
                              void* d_out, int out_size, void* d_ws, size_t ws_size,
                              hipStream_t stream) {
    const float* f1  = (const float*)d_in[0];
    const float* f2  = (const float*)d_in[1];
    // d_in[2] = mask_c1 (all true -> nv=nh=10 hardcoded)
    const float* wci = (const float*)d_in[3];
    const float* bci = (const float*)d_in[4];
    const float* w1i = (const float*)d_in[5];
    const float* w2i = (const float*)d_in[6];
    const float* gi  = (const float*)d_in[7];
    const float* bli = (const float*)d_in[8];
    const float* wcd = (const float*)d_in[9];
    const float* bcd = (const float*)d_in[10];
    const float* w1d = (const float*)d_in[11];
    const float* w2d = (const float*)d_in[12];
    const float* gd  = (const float*)d_in[13];
    const float* bld = (const float*)d_in[14];
    const float* lsc = (const float*)d_in[15];

    float* partial = (float*)d_ws;                   // 2*4*25600 floats = 800 KB
    float* e       = partial + 2 * BATCH * HW;       // 2*400*128 floats = 400 KB
    float* out = (float*)d_out;

    // zero the conv partial buffer (ws is poisoned 0xAA before every launch)
    hipMemsetAsync(partial, 0, (size_t)2 * BATCH * HW * sizeof(float), stream);

    // K1: 16 ch-groups x 8 planes x 5 px-chunks = 640 blocks
    conv_partial_kernel<<<640, 256, 0, stream>>>(f1, f2, wci, wcd, partial);
    // K2: 2 branches * 100 row-groups of 4
    mlp_ln_kernel<<<200, 256, 0, stream>>>(partial, bci, bcd,
                                           w1i, w2i, gi, bli,
                                           w1d, w2d, gd, bld, e);
    // K3: 40000 (b,n,m) triples
    logits_kernel<<<(BATCH * NPATCH * NPATCH + 255) / 256, 256, 0, stream>>>(e, lsc, out);
}

// Round 4
// 291.071 us; speedup vs baseline: 1.0850x; 1.0850x over previous
//
#include <hip/hip_runtime.h>
#include <math.h>

// Problem constants (mask is all-true 160x160 -> nv=nh=10, fixed)
#define CPS 16
#define ENC 128
#define NH 10
#define NPATCH 100      // patches per batch image
#define BATCH 4
#define CCH 256         // input channels
#define WIDTH 160
#define HW 25600        // 160*160
#define ROWS_TOTAL 400  // BATCH*NPATCH
#define CSPLIT 8        // channel split across blocks
#define CHPG 32         // channels per split group

// ---------------------------------------------------------------------------
// K1: conv partials with forced memory-level parallelism.
// Grid = 25 px-chunks x 8 splits x 8 planes = 1600 blocks x 4 waves
// = 25 waves/CU. Each wave: 32 channels x 1KB loads over one 256-px window,
// batched 16 loads at a time (explicit v[16] array -> ~16KB in flight/wave;
// launch_bounds(256,4) gives VGPR headroom of 128). Non-atomic partial
// write to partial[split][plane][px]; reduction fused into K2's gather.
// plane is the fastest-varying blockIdx component so consecutive blocks
// (round-robin across XCDs) touch distinct 25MB regions.
// ---------------------------------------------------------------------------
__global__ __launch_bounds__(256, 4) void conv_partial_kernel(
    const float* __restrict__ f1, const float* __restrict__ f2,
    const float* __restrict__ wci, const float* __restrict__ wcd,
    float* __restrict__ partial)
{
    int lane = threadIdx.x & 63;
    int wv   = threadIdx.x >> 6;

    int bid   = blockIdx.x;          // 0..1599
    int plane = bid & 7;             // branch*4 + b  (fastest-varying)
    int split = (bid >> 3) & 7;      // channel group
    int chunk = bid >> 6;            // 0..24
    int branch = plane >> 2;
    int b      = plane & 3;

    const float* f    = branch ? f2  : f1;
    const float* wsel = (branch ? wcd : wci) + split * CHPG;  // uniform

    int px = chunk * 1024 + wv * 256 + lane * 4;
    const float* fb = f + ((size_t)(b * CCH + split * CHPG)) * HW + px;

    float4 acc = make_float4(0.f, 0.f, 0.f, 0.f);
    #pragma unroll
    for (int h = 0; h < 2; ++h) {
        float4 v[16];
        #pragma unroll
        for (int j = 0; j < 16; ++j)               // 16 independent 1KB loads
            v[j] = *(const float4*)(fb + (size_t)(h * 16 + j) * HW);
        #pragma unroll
        for (int j = 0; j < 16; ++j) {
            float wc = wsel[h * 16 + j];           // wave-uniform scalar load
            acc.x = fmaf(v[j].x, wc, acc.x);
            acc.y = fmaf(v[j].y, wc, acc.y);
            acc.z = fmaf(v[j].z, wc, acc.z);
            acc.w = fmaf(v[j].w, wc, acc.w);
        }
    }

    *(float4*)(partial + ((size_t)(split * 8 + plane)) * HW + px) = acc;
}

// ---------------------------------------------------------------------------
// K2: gather conv partials (8-way reduce) + bias + ReLU in patch layout,
// then per-row MLP (256 -> relu(w1) 256 -> w2 128) + LayerNorm.
// 4 rows/block, 256 threads.
// ---------------------------------------------------------------------------
__global__ __launch_bounds__(256) void mlp_ln_kernel(
    const float* __restrict__ partial,
    const float* __restrict__ bci,  const float* __restrict__ bcd,
    const float* __restrict__ w1i, const float* __restrict__ w2i,
    const float* __restrict__ gi,  const float* __restrict__ bli,
    const float* __restrict__ w1d, const float* __restrict__ w2d,
    const float* __restrict__ gd,  const float* __restrict__ bld,
    float* __restrict__ e)
{
    const int R = 4;
    __shared__ float xs[R][256];
    __shared__ float ys[R][256];
    __shared__ float zs[R][ENC];

    int tid    = threadIdx.x;
    int branch = blockIdx.x / 100;            // uniform
    int row0   = (blockIdx.x % 100) * R;

    const float* w1 = branch ? w1d : w1i;
    const float* w2 = branch ? w2d : w2i;
    const float* g  = branch ? gd  : gi;
    const float* bl = branch ? bld : bli;
    float bias      = branch ? bcd[0] : bci[0];

    // gather + 8-way partial reduce: row p, element j=tid -> pixel in plane
    {
        int hh = tid >> 4, ww = tid & 15;
        #pragma unroll
        for (int r = 0; r < R; ++r) {
            int prow  = row0 + r;                  // 0..399
            int b     = prow / 100;
            int patch = prow % 100;
            int pv = patch / 10, ph = patch % 10;
            int pixel = (pv * 16 + hh) * WIDTH + ph * 16 + ww;
            int plane = branch * BATCH + b;
            float v = bias;
            #pragma unroll
            for (int s = 0; s < CSPLIT; ++s)
                v += partial[((size_t)(s * 8 + plane)) * HW + pixel];
            xs[r][tid] = fmaxf(v, 0.f);
        }
    }
    __syncthreads();

    // GEMM1: y[r][tid] = relu(dot(xs[r], w1[tid,:]))
    {
        float acc[R] = {0.f, 0.f, 0.f, 0.f};
        const float4* w1r = (const float4*)(w1 + (size_t)tid * 256);
        #pragma unroll 4
        for (int c4 = 0; c4 < 64; ++c4) {
            float4 wv = w1r[c4];
            #pragma unroll
            for (int r = 0; r < R; ++r) {
                float4 xv = *(const float4*)(&xs[r][c4 * 4]);   // LDS broadcast
                acc[r] = fmaf(xv.x, wv.x, acc[r]);
                acc[r] = fmaf(xv.y, wv.y, acc[r]);
                acc[r] = fmaf(xv.z, wv.z, acc[r]);
                acc[r] = fmaf(xv.w, wv.w, acc[r]);
            }
        }
        #pragma unroll
        for (int r = 0; r < R; ++r) ys[r][tid] = fmaxf(acc[r], 0.f);
    }
    __syncthreads();

    // GEMM2: z[r][m] = dot(ys[r], w2[m,:])  (512 outputs, 2 per thread)
    #pragma unroll
    for (int i = 0; i < 2; ++i) {
        int idx = tid + 256 * i;
        int r = idx >> 7, m = idx & 127;
        float acc = 0.f;
        const float4* w2r = (const float4*)(w2 + (size_t)m * 256);
        #pragma unroll 4
        for (int c4 = 0; c4 < 64; ++c4) {
            float4 wv = w2r[c4];
            float4 yv = *(const float4*)(&ys[r][c4 * 4]);       // LDS broadcast
            acc = fmaf(yv.x, wv.x, acc);
            acc = fmaf(yv.y, wv.y, acc);
            acc = fmaf(yv.z, wv.z, acc);
            acc = fmaf(yv.w, wv.w, acc);
        }
        zs[r][m] = acc;
    }
    __syncthreads();

    // LayerNorm: wave r handles row r (each lane owns 2 of 128 elements)
    int r = tid >> 6, lane = tid & 63;
    float a  = zs[r][lane];
    float b2 = zs[r][lane + 64];
    float s = a + b2;
    float q = a * a + b2 * b2;
    #pragma unroll
    for (int off = 32; off >= 1; off >>= 1) {
        s += __shfl_xor(s, off);
        q += __shfl_xor(q, off);
    }
    float mu  = s * (1.f / 128.f);
    float var = q * (1.f / 128.f) - mu * mu;
    float inv = 1.f / sqrtf(var + 1e-5f);
    float* erow = e + ((size_t)(branch * ROWS_TOTAL + row0 + r)) * ENC;
    erow[lane]      = (a  - mu) * inv * g[lane]      + bl[lane];
    erow[lane + 64] = (b2 - mu) * inv * g[lane + 64] + bl[lane + 64];
}

// ---------------------------------------------------------------------------
// K3: logits = scale * e1[b] @ e2[b]^T  (4 x 100 x 100) + transposed copy
// ---------------------------------------------------------------------------
__global__ __launch_bounds__(256) void logits_kernel(
    const float* __restrict__ e, const float* __restrict__ lsc,
    float* __restrict__ out)
{
    int gidx = blockIdx.x * 256 + threadIdx.x;
    if (gidx >= BATCH * NPATCH * NPATCH) return;
    float scale = expf(lsc[0]);

    int b    = gidx / (NPATCH * NPATCH);
    int rrem = gidx % (NPATCH * NPATCH);
    int n = rrem / NPATCH, m = rrem % NPATCH;

    const float4* e1 = (const float4*)(e + (size_t)(b * NPATCH + n) * ENC);
    const float4* e2 = (const float4*)(e + (size_t)(ROWS_TOTAL + b * NPATCH + m) * ENC);
    float acc = 0.f;
    #pragma unroll 8
    for (int c4 = 0; c4 < ENC / 4; ++c4) {
        float4 av = e1[c4], bv = e2[c4];
        acc = fmaf(av.x, bv.x, acc);
        acc = fmaf(av.y, bv.y, acc);
        acc = fmaf(av.z, bv.z, acc);
        acc = fmaf(av.w, bv.w, acc);
    }
    float L = scale * acc;
    out[gidx] = L;                                              // logits_per_img
    out[BATCH * NPATCH * NPATCH + b * NPATCH * NPATCH + m * NPATCH + n] = L; // transposed
}

extern "C" void kernel_launch(void* const* d_in, const int* in_sizes, int n_in,
                              void* d_out, int out_size, void* d_ws, size_t ws_size,
                              hipStream_t stream) {
    const float* f1  = (const float*)d_in[0];
    const float* f2  = (const float*)d_in[1];
    // d_in[2] = mask_c1 (all true -> nv=nh=10 hardcoded)
    const float* wci = (const float*)d_in[3];
    const float* bci = (const float*)d_in[4];
    const float* w1i = (const float*)d_in[5];
    const float* w2i = (const float*)d_in[6];
    const float* gi  = (const float*)d_in[7];
    const float* bli = (const float*)d_in[8];
    const float* wcd = (const float*)d_in[9];
    const float* bcd = (const float*)d_in[10];
    const float* w1d = (const float*)d_in[11];
    const float* w2d = (const float*)d_in[12];
    const float* gd  = (const float*)d_in[13];
    const float* bld = (const float*)d_in[14];
    const float* lsc = (const float*)d_in[15];

    float* partial = (float*)d_ws;                       // 8*8*25600*4B = 6.55 MB
    float* e       = partial + CSPLIT * 8 * HW;          // 2*400*128 floats = 400 KB
    float* out = (float*)d_out;

    // K1: 25 chunks x 8 splits x 8 planes = 1600 blocks (plane fastest)
    conv_partial_kernel<<<1600, 256, 0, stream>>>(f1, f2, wci, wcd, partial);
    // K2: 2 branches * 100 row-groups of 4 (8-way partial reduce fused in)
    mlp_ln_kernel<<<200, 256, 0, stream>>>(partial, bci, bcd,
                                           w1i, w2i, gi, bli,
                                           w1d, w2d, gd, bld, e);
    // K3: 40000 (b,n,m) triples
    logits_kernel<<<(BATCH * NPATCH * NPATCH + 255) / 256, 256, 0, stream>>>(e, lsc, out);
}

// Round 6
// 267.328 us; speedup vs baseline: 1.1813x; 1.0888x over previous
//
#include <hip/hip_runtime.h>
#include <math.h>

// Problem constants (mask is all-true 160x160 -> nv=nh=10, fixed)
#define CPS 16
#define ENC 128
#define NH 10
#define NPATCH 100      // patches per batch image
#define BATCH 4
#define CCH 256         // input channels
#define WIDTH 160
#define HW 25600        // 160*160
#define ROWS_TOTAL 400  // BATCH*NPATCH
#define CSPLIT 8        // channel split across blocks
#define CHPG 32         // channels per split group

typedef float vf4 __attribute__((ext_vector_type(4)));  // nt-load-compatible

// ---------------------------------------------------------------------------
// K1: conv partials, R4 structure + NONTEMPORAL feature loads (A/B test:
// does nt change the ~2.6 TB/s CU-side read ceiling by altering L2/L3
// allocation for the streaming tensors?). Everything else identical to R4.
// ---------------------------------------------------------------------------
__global__ __launch_bounds__(256, 4) void conv_partial_kernel(
    const float* __restrict__ f1, const float* __restrict__ f2,
    const float* __restrict__ wci, const float* __restrict__ wcd,
    float* __restrict__ partial)
{
    int lane = threadIdx.x & 63;
    int wv   = threadIdx.x >> 6;

    int bid   = blockIdx.x;          // 0..1599
    int plane = bid & 7;             // branch*4 + b  (fastest-varying)
    int split = (bid >> 3) & 7;      // channel group
    int chunk = bid >> 6;            // 0..24
    int branch = plane >> 2;
    int b      = plane & 3;

    const float* f    = branch ? f2  : f1;
    const float* wsel = (branch ? wcd : wci) + split * CHPG;  // uniform

    int px = chunk * 1024 + wv * 256 + lane * 4;
    const float* fb = f + ((size_t)(b * CCH + split * CHPG)) * HW + px;

    vf4 acc = (vf4)(0.f);
    #pragma unroll
    for (int h = 0; h < 2; ++h) {
        vf4 v[16];
        #pragma unroll
        for (int j = 0; j < 16; ++j)               // 16 independent 1KB nt loads
            v[j] = __builtin_nontemporal_load(
                       (const vf4*)(fb + (size_t)(h * 16 + j) * HW));
        #pragma unroll
        for (int j = 0; j < 16; ++j) {
            float wc = wsel[h * 16 + j];           // wave-uniform scalar load
            acc += v[j] * wc;
        }
    }

    *(vf4*)(partial + ((size_t)(split * 8 + plane)) * HW + px) = acc;
}

// ---------------------------------------------------------------------------
// K2: gather conv partials (8-way reduce) + bias + ReLU in patch layout,
// then per-row MLP (256 -> relu(w1) 256 -> w2 128) + LayerNorm.
// 4 rows/block, 256 threads.
// ---------------------------------------------------------------------------
__global__ __launch_bounds__(256) void mlp_ln_kernel(
    const float* __restrict__ partial,
    const float* __restrict__ bci,  const float* __restrict__ bcd,
    const float* __restrict__ w1i, const float* __restrict__ w2i,
    const float* __restrict__ gi,  const float* __restrict__ bli,
    const float* __restrict__ w1d, const float* __restrict__ w2d,
    const float* __restrict__ gd,  const float* __restrict__ bld,
    float* __restrict__ e)
{
    const int R = 4;
    __shared__ float xs[R][256];
    __shared__ float ys[R][256];
    __shared__ float zs[R][ENC];

    int tid    = threadIdx.x;
    int branch = blockIdx.x / 100;            // uniform
    int row0   = (blockIdx.x % 100) * R;

    const float* w1 = branch ? w1d : w1i;
    const float* w2 = branch ? w2d : w2i;
    const float* g  = branch ? gd  : gi;
    const float* bl = branch ? bld : bli;
    float bias      = branch ? bcd[0] : bci[0];

    // gather + 8-way partial reduce: row p, element j=tid -> pixel in plane
    {
        int hh = tid >> 4, ww = tid & 15;
        #pragma unroll
        for (int r = 0; r < R; ++r) {
            int prow  = row0 + r;                  // 0..399
            int b     = prow / 100;
            int patch = prow % 100;
            int pv = patch / 10, ph = patch % 10;
            int pixel = (pv * 16 + hh) * WIDTH + ph * 16 + ww;
            int plane = branch * BATCH + b;
            float v = bias;
            #pragma unroll
            for (int s = 0; s < CSPLIT; ++s)
                v += partial[((size_t)(s * 8 + plane)) * HW + pixel];
            xs[r][tid] = fmaxf(v, 0.f);
        }
    }
    __syncthreads();

    // GEMM1: y[r][tid] = relu(dot(xs[r], w1[tid,:]))
    {
        float acc[R] = {0.f, 0.f, 0.f, 0.f};
        const float4* w1r = (const float4*)(w1 + (size_t)tid * 256);
        #pragma unroll 4
        for (int c4 = 0; c4 < 64; ++c4) {
            float4 wv = w1r[c4];
            #pragma unroll
            for (int r = 0; r < R; ++r) {
                float4 xv = *(const float4*)(&xs[r][c4 * 4]);   // LDS broadcast
                acc[r] = fmaf(xv.x, wv.x, acc[r]);
                acc[r] = fmaf(xv.y, wv.y, acc[r]);
                acc[r] = fmaf(xv.z, wv.z, acc[r]);
                acc[r] = fmaf(xv.w, wv.w, acc[r]);
            }
        }
        #pragma unroll
        for (int r = 0; r < R; ++r) ys[r][tid] = fmaxf(acc[r], 0.f);
    }
    __syncthreads();

    // GEMM2: z[r][m] = dot(ys[r], w2[m,:])  (512 outputs, 2 per thread)
    #pragma unroll
    for (int i = 0; i < 2; ++i) {
        int idx = tid + 256 * i;
        int r = idx >> 7, m = idx & 127;
        float acc = 0.f;
        const float4* w2r = (const float4*)(w2 + (size_t)m * 256);
        #pragma unroll 4
        for (int c4 = 0; c4 < 64; ++c4) {
            float4 wv = w2r[c4];
            float4 yv = *(const float4*)(&ys[r][c4 * 4]);       // LDS broadcast
            acc = fmaf(yv.x, wv.x, acc);
            acc = fmaf(yv.y, wv.y, acc);
            acc = fmaf(yv.z, wv.z, acc);
            acc = fmaf(yv.w, wv.w, acc);
        }
        zs[r][m] = acc;
    }
    __syncthreads();

    // LayerNorm: wave r handles row r (each lane owns 2 of 128 elements)
    int r = tid >> 6, lane = tid & 63;
    float a  = zs[r][lane];
    float b2 = zs[r][lane + 64];
    float s = a + b2;
    float q = a * a + b2 * b2;
    #pragma unroll
    for (int off = 32; off >= 1; off >>= 1) {
        s += __shfl_xor(s, off);
        q += __shfl_xor(q, off);
    }
    float mu  = s * (1.f / 128.f);
    float var = q * (1.f / 128.f) - mu * mu;
    float inv = 1.f / sqrtf(var + 1e-5f);
    float* erow = e + ((size_t)(branch * ROWS_TOTAL + row0 + r)) * ENC;
    erow[lane]      = (a  - mu) * inv * g[lane]      + bl[lane];
    erow[lane + 64] = (b2 - mu) * inv * g[lane + 64] + bl[lane + 64];
}

// ---------------------------------------------------------------------------
// K3: logits = scale * e1[b] @ e2[b]^T  (4 x 100 x 100) + transposed copy
// ---------------------------------------------------------------------------
__global__ __launch_bounds__(256) void logits_kernel(
    const float* __restrict__ e, const float* __restrict__ lsc,
    float* __restrict__ out)
{
    int gidx = blockIdx.x * 256 + threadIdx.x;
    if (gidx >= BATCH * NPATCH * NPATCH) return;
    float scale = expf(lsc[0]);

    int b    = gidx / (NPATCH * NPATCH);
    int rrem = gidx % (NPATCH * NPATCH);
    int n = rrem / NPATCH, m = rrem % NPATCH;

    const float4* e1 = (const float4*)(e + (size_t)(b * NPATCH + n) * ENC);
    const float4* e2 = (const float4*)(e + (size_t)(ROWS_TOTAL + b * NPATCH + m) * ENC);
    float acc = 0.f;
    #pragma unroll 8
    for (int c4 = 0; c4 < ENC / 4; ++c4) {
        float4 av = e1[c4], bv = e2[c4];
        acc = fmaf(av.x, bv.x, acc);
        acc = fmaf(av.y, bv.y, acc);
        acc = fmaf(av.z, bv.z, acc);
        acc = fmaf(av.w, bv.w, acc);
    }
    float L = scale * acc;
    out[gidx] = L;                                              // logits_per_img
    out[BATCH * NPATCH * NPATCH + b * NPATCH * NPATCH + m * NPATCH + n] = L; // transposed
}

extern "C" void kernel_launch(void* const* d_in, const int* in_sizes, int n_in,
                              void* d_out, int out_size, void* d_ws, size_t ws_size,
                              hipStream_t stream) {
    const float* f1  = (const float*)d_in[0];
    const float* f2  = (const float*)d_in[1];
    // d_in[2] = mask_c1 (all true -> nv=nh=10 hardcoded)
    const float* wci = (const float*)d_in[3];
    const float* bci = (const float*)d_in[4];
    const float* w1i = (const float*)d_in[5];
    const float* w2i = (const float*)d_in[6];
    const float* gi  = (const float*)d_in[7];
    const float* bli = (const float*)d_in[8];
    const float* wcd = (const float*)d_in[9];
    const float* bcd = (const float*)d_in[10];
    const float* w1d = (const float*)d_in[11];
    const float* w2d = (const float*)d_in[12];
    const float* gd  = (const float*)d_in[13];
    const float* bld = (const float*)d_in[14];
    const float* lsc = (const float*)d_in[15];

    float* partial = (float*)d_ws;                       // 8*8*25600*4B = 6.55 MB
    float* e       = partial + CSPLIT * 8 * HW;          // 2*400*128 floats = 400 KB
    float* out = (float*)d_out;

    // K1: 25 chunks x 8 splits x 8 planes = 1600 blocks (plane fastest)
    conv_partial_kernel<<<1600, 256, 0, stream>>>(f1, f2, wci, wcd, partial);
    // K2: 2 branches * 100 row-groups of 4 (8-way partial reduce fused in)
    mlp_ln_kernel<<<200, 256, 0, stream>>>(partial, bci, bcd,
                                           w1i, w2i, gi, bli,
                                           w1d, w2d, gd, bld, e);
    // K3: 40000 (b,n,m) triples
    logits_kernel<<<(BATCH * NPATCH * NPATCH + 255) / 256, 256, 0, stream>>>(e, lsc, out);
}